// Round 9
// baseline (43.952 us; speedup 1.0000x reference)
//
#include <hip/hip_runtime.h>
#include <math.h>

// Problem constants (match reference)
constexpr int B_ = 32, Q_ = 500, N_ = 200, K_ = 16, C_ = 92;
constexpr int TWO_K = 32;
constexpr int TB = 128;            // threads per block (both kernels)
constexpr int QT = 128;            // q-tile (thread = q)
constexpr int NT = 16;             // n-tile (wave-uniform n)
constexpr int NSPL = 13;           // ceil(200/16); last split overlaps (benign rewrite)
constexpr int TST = 36;            // sT row stride floats (144 B, 16B-aligned)
constexpr int OST = 17;            // sOut row stride (odd -> conflict-free)
constexpr float EPS_ = 1e-6f;
constexpr float POLY_SCALE = 5.0f / 32.0f;   // POLY_COST / (2K)

__device__ __forceinline__ float rcpf_(float x) { return __builtin_amdgcn_rcpf(x); }

// ---------------- kernel A: probT[b][c][q] = softmax(logits)[b][q][c] ----------------
__global__ __launch_bounds__(TB)
void softmax_T_kernel(const float* __restrict__ logits, float* __restrict__ probT)
{
    const int gid = blockIdx.x * TB + threadIdx.x;   // flat b*Q+q, 16000 exact
    const int b = gid / Q_;
    const int q = gid - b * Q_;
    const float4* lg4 = reinterpret_cast<const float4*>(logits + (size_t)gid * C_);

    float mx = -INFINITY;
    #pragma unroll
    for (int j = 0; j < 23; ++j) {
        float4 v = lg4[j];
        mx = fmaxf(mx, fmaxf(fmaxf(v.x, v.y), fmaxf(v.z, v.w)));
    }
    float s = 0.0f;
    #pragma unroll
    for (int j = 0; j < 23; ++j) {
        float4 v = lg4[j];
        s += __expf(v.x - mx) + __expf(v.y - mx) + __expf(v.z - mx) + __expf(v.w - mx);
    }
    const float rs = 1.0f / s;

    float* base = probT + (size_t)b * C_ * Q_ + q;   // + c*Q below (coalesced in q)
    #pragma unroll
    for (int j = 0; j < 23; ++j) {
        float4 v = lg4[j];
        base[(size_t)(4 * j + 0) * Q_] = __expf(v.x - mx) * rs;
        base[(size_t)(4 * j + 1) * Q_] = __expf(v.y - mx) * rs;
        base[(size_t)(4 * j + 2) * Q_] = __expf(v.z - mx) * rs;
        base[(size_t)(4 * j + 3) * Q_] = __expf(v.w - mx) * rs;
    }
}

// ---------------- kernel B: cost matrix ----------------
__global__ __launch_bounds__(TB)
void cost_kernel(const float* __restrict__ ppoly,    // (B,Q,K,2)
                 const int*   __restrict__ labels,   // (B,N)
                 const float* __restrict__ tpoly,    // (B,N,K,2)
                 const float* __restrict__ probT,    // (B,C,Q) in d_ws
                 float* __restrict__ out)            // (B,Q,N)
{
    __shared__ float sT[NT * TST];     // 16 target rows (2304 B)
    __shared__ float sTB[NT * 8];      // tgt bbox(4)+area (512 B)
    __shared__ int   sLbl[NT];
    __shared__ float sOut[QT * OST];   // (8704 B)  -> total ~11.6 KB

    const int tid = threadIdx.x;
    const int q0 = min((int)blockIdx.x * QT, Q_ - QT);
    const int n0 = min((int)blockIdx.y * NT, N_ - NT);
    const int b  = blockIdx.z;

    // stage 16 target rows: 128 threads x one float4 (coalesced)
    {
        int r = tid >> 3, c = tid & 7;
        float4 v = reinterpret_cast<const float4*>(
            tpoly + (size_t)(b * N_ + n0 + r) * TWO_K)[c];
        *reinterpret_cast<float4*>(&sT[r * TST + c * 4]) = v;
    }
    if (tid < NT) sLbl[tid] = labels[b * N_ + n0 + tid];

    // per-thread pred polyline + bbox (registers; NO launch-bounds strangle)
    const int q = q0 + tid;
    float px[K_], py[K_];
    float pxm = INFINITY, pxM = -INFINITY, pym = INFINITY, pyM = -INFINITY;
    {
        const float4* pr4 = reinterpret_cast<const float4*>(
            ppoly + (size_t)(b * Q_ + q) * TWO_K);
        #pragma unroll
        for (int m = 0; m < 8; ++m) {
            float4 v = pr4[m];
            px[2 * m] = v.x;  py[2 * m] = v.y;
            px[2 * m + 1] = v.z;  py[2 * m + 1] = v.w;
            pxm = fminf(pxm, fminf(v.x, v.z)); pxM = fmaxf(pxM, fmaxf(v.x, v.z));
            pym = fminf(pym, fminf(v.y, v.w)); pyM = fmaxf(pyM, fmaxf(v.y, v.w));
        }
    }
    const float parea = (pxM - pxm) * (pyM - pym);
    __syncthreads();

    // tgt bboxes (threads 0..15, one row each)
    if (tid < NT) {
        const float2* tr = reinterpret_cast<const float2*>(&sT[tid * TST]);
        float xm = INFINITY, ym = INFINITY, xM = -INFINITY, yM = -INFINITY;
        #pragma unroll
        for (int k = 0; k < K_; ++k) {
            float2 t = tr[k];
            xm = fminf(xm, t.x); xM = fmaxf(xM, t.x);
            ym = fminf(ym, t.y); yM = fmaxf(yM, t.y);
        }
        sTB[tid * 8 + 0] = xm; sTB[tid * 8 + 1] = ym;
        sTB[tid * 8 + 2] = xM; sTB[tid * 8 + 3] = yM;
        sTB[tid * 8 + 4] = (xM - xm) * (yM - ym);
    }
    __syncthreads();

    const float* pTb = probT + (size_t)b * C_ * Q_ + q;   // + lbl*Q per n

    #pragma unroll 2
    for (int nl = 0; nl < NT; ++nl) {
        // whole target row -> registers via 8 uniform (broadcast) b128 reads
        const float4* t4p = reinterpret_cast<const float4*>(&sT[nl * TST]);
        float4 tq[8];
        #pragma unroll
        for (int m = 0; m < 8; ++m) tq[m] = t4p[m];

        float f0 = 0, f1 = 0, r0 = 0, r1 = 0;   // 4 independent chains
        #pragma unroll
        for (int m = 0; m < 8; ++m) {
            const int k0 = 2 * m, k1 = 2 * m + 1;
            f0 += fabsf(px[k0] - tq[m].x) + fabsf(py[k0] - tq[m].y);
            f1 += fabsf(px[k1] - tq[m].z) + fabsf(py[k1] - tq[m].w);
            r0 += fabsf(px[15 - k0] - tq[m].x) + fabsf(py[15 - k0] - tq[m].y);
            r1 += fabsf(px[15 - k1] - tq[m].z) + fabsf(py[15 - k1] - tq[m].w);
        }
        float cpoly = fminf(f0 + f1, r0 + r1);

        // class term: one coalesced L2 load (probT row contiguous in q)
        int lbl = __builtin_amdgcn_readfirstlane(sLbl[nl]);
        float pr = pTb[(size_t)lbl * Q_];

        float tx0 = sTB[nl * 8 + 0], ty0 = sTB[nl * 8 + 1];
        float tx1 = sTB[nl * 8 + 2], ty1 = sTB[nl * 8 + 3];
        float ta  = sTB[nl * 8 + 4];
        float ix0 = fmaxf(pxm, tx0), iy0 = fmaxf(pym, ty0);
        float ix1 = fminf(pxM, tx1), iy1 = fminf(pyM, ty1);
        float inter = fmaxf(ix1 - ix0, 0.0f) * fmaxf(iy1 - iy0, 0.0f);
        float uni = parea + ta - inter;
        float iou = inter * rcpf_(fmaxf(uni, EPS_));
        float cx0 = fminf(pxm, tx0), cy0 = fminf(pym, ty0);
        float cx1 = fmaxf(pxM, tx1), cy1 = fmaxf(pyM, ty1);
        float ca = (cx1 - cx0) * (cy1 - cy0);
        float giou = iou - (ca - uni) * rcpf_(fmaxf(ca, EPS_));

        sOut[tid * OST + nl] = fmaf(cpoly, POLY_SCALE, -pr) - giou;
    }
    __syncthreads();

    // coalesced store: 64 lanes = 4 q-rows x 16 n (64B-aligned runs for n0%16==0)
    float* ob = out + (size_t)b * Q_ * N_;
    #pragma unroll
    for (int j = 0; j < QT * NT / TB; ++j) {   // 16 iterations
        int g = tid + j * TB;
        int qq = g >> 4, nn = g & 15;
        ob[(size_t)(q0 + qq) * N_ + n0 + nn] = sOut[qq * OST + nn];
    }
}

extern "C" void kernel_launch(void* const* d_in, const int* in_sizes, int n_in,
                              void* d_out, int out_size, void* d_ws, size_t ws_size,
                              hipStream_t stream) {
    const float* logits = (const float*)d_in[0];   // (B,Q,C)
    const float* ppoly  = (const float*)d_in[1];   // (B,Q,K,2)
    const int*   labels = (const int*)d_in[2];     // (B,N)
    const float* tpoly  = (const float*)d_in[3];   // (B,N,K,2)
    float* outp  = (float*)d_out;                  // (B,Q,N)
    float* probT = (float*)d_ws;                   // (B,C,Q) = 5.888 MB scratch

    softmax_T_kernel<<<(B_ * Q_) / TB, TB, 0, stream>>>(logits, probT);

    dim3 grid((Q_ + QT - 1) / QT, NSPL, B_);       // (4, 13, 32) = 1664 blocks
    cost_kernel<<<grid, TB, 0, stream>>>(ppoly, labels, tpoly, probT, outp);
}